// Round 7
// baseline (905.159 us; speedup 1.0000x reference)
//
#include <hip/hip_runtime.h>
#include <cstdint>
#include <cstddef>

typedef __bf16 bf16;
typedef __attribute__((ext_vector_type(8))) __bf16 bf16x8;
typedef __attribute__((ext_vector_type(2))) __bf16 bf16x2;
typedef __attribute__((ext_vector_type(4))) float f32x4;
typedef __attribute__((ext_vector_type(2))) float f32x2;
typedef __attribute__((ext_vector_type(4))) int i32x4;

#define DIMN 4096
#define SEQ 512
#define MAXSEQ 2048
#define NHEAD 32
#define HD 128

#define BM 128
#define BN 128
#define BK 32    // bf16 core: 32 elems = 64 B rows

// ---------------- async global->LDS (wave-uniform base + lane*16) ----------
__device__ __forceinline__ void gld_lds16(const void* g, void* l) {
  __builtin_amdgcn_global_load_lds(
      (const __attribute__((address_space(1))) unsigned int*)g,
      (__attribute__((address_space(3))) unsigned int*)l, 16, 0, 0);
}

// ---------------- bf16 bt-GEMM core (m97 lineage, proven) ------------------
__device__ __forceinline__ void gemm_core(const bf16* Ablk, const bf16* Bblk,
                                          int lda, int ldb, int kmax,
                                          f32x4 acc[4][4], bf16* As, bf16* Bs) {
  const int tid = threadIdx.x;
  const int wave = tid >> 6;
  const int lane = tid & 63;
  const int wm = (wave >> 1) * 64;
  const int wn = (wave & 1) * 64;
  const int lrow = lane & 15;
  const int lkq8 = (lane >> 4) * 8;
  const int srow = wave * 32 + (lane >> 2);
  const int scol = (lane & 3) * 8;
  const bf16* Ag = Ablk + (size_t)srow * lda + scol;
  const bf16* Bg = Bblk + (size_t)srow * ldb + scol;
  bf16* lA = As + wave * 32 * BK;
  bf16* lB = Bs + wave * 32 * BK;

  for (int k0 = 0; k0 < kmax; k0 += BK) {
    __syncthreads();
    gld_lds16(Ag + k0, lA);
    gld_lds16(Ag + k0 + (size_t)16 * lda, lA + 16 * BK);
    gld_lds16(Bg + k0, lB);
    gld_lds16(Bg + k0 + (size_t)16 * ldb, lB + 16 * BK);
    __syncthreads();
    bf16x8 a[4], b[4];
#pragma unroll
    for (int i = 0; i < 4; ++i)
      a[i] = *(const bf16x8*)(As + (wm + i * 16 + lrow) * BK + lkq8);
#pragma unroll
    for (int i = 0; i < 4; ++i)
      b[i] = *(const bf16x8*)(Bs + (wn + i * 16 + lrow) * BK + lkq8);
#pragma unroll
    for (int mi = 0; mi < 4; ++mi)
#pragma unroll
      for (int ni = 0; ni < 4; ++ni)
        acc[mi][ni] = __builtin_amdgcn_mfma_f32_16x16x32_bf16(a[mi], b[ni], acc[mi][ni], 0, 0, 0);
  }
}

// ===========================================================================
// int8 128x256-tile 2-phase/K-tile GEMM core (round-7 geometry fix)
//
// Round-6 post-mortem: 256^2 tile passed (race-free) but grid-quantized
// (QKV 384 blocks -> 2 rounds for 1.5 rounds of work; out-proj 128 blocks
// -> half GPU). This version keeps the identical phase micro-structure
// (16 MFMA + interleaved staging per phase, counted vmcnt, raw s_barrier,
// setprio) but at 128x256 tile: QKV = 768 blocks = 3 exact rounds,
// out-proj = 256 blocks = 1 exact round. 8 waves, per-wave C = 64x64.
// K-tile = 128 (2x mfma_i32_16x16x64 per frag, h0/h1 = k 0-63/64-127).
// LDS 96 KiB: 2 bufs x { A[2][128][64] 16K + B[2][256][64] 32K }.
// Granule swizzle: LDS granule g of row r holds global granule g^(r&3)
// (pre-swizzled global source, linear LDS dest); frag read at g=q^(lrow&3).
// Schedule per K-tile t (CUR = t-parity buf, OTH = other):
//   p1: ds_read h0 frags | stage A.h1,B.h1(t+1)->OTH | bar | 16 MFMA | bar
//   p2: ds_read h1 frags | stage A.h0,B.h0(t+2)->CUR | vmcnt(3) | bar | 16 MFMA | bar
// Invariant (same proof as round-6's passed kernel, 3 calls/half-pair):
// at p2's vmcnt(3) the oldest 6 outstanding (= all tile t+1 data) are
// complete; 3 (h0(t+2)->CUR) stay in flight. Every region is overwritten
// only after the barrier that retired its last read. Tail stages read
// a few KB past the operand into adjacent mapped ws -> dead LDS, harmless.
// ===========================================================================

#define PBAR do {                              \
    asm volatile("" ::: "memory");             \
    __builtin_amdgcn_sched_barrier(0);         \
    __builtin_amdgcn_s_barrier();              \
    __builtin_amdgcn_sched_barrier(0);         \
    asm volatile("" ::: "memory");             \
  } while (0)

// A half-tile = 128x64 i8 = 8 KB = one block-wide load (512 lanes x 16 B)
#define STG_A(KT, H, LB) do {                                    \
    const char* _g = Asrc + (KT) * 128 + (H) * 64;               \
    gld_lds16(_g, (LB) + (H) * 8192 + sdst);                     \
  } while (0)
// B half-tile = 256x64 i8 = 16 KB = two block-wide loads
#define STG_B(KT, H, LB) do {                                    \
    const char* _g = Bsrc + (KT) * 128 + (H) * 64;               \
    char* _l = (LB) + 16384 + (H) * 16384 + sdst;                \
    gld_lds16(_g, _l);                                           \
    gld_lds16(_g + (size_t)128 * DIMN, _l + 8192);               \
  } while (0)

#define LDA8(DST, MI, H, LB) \
  DST = *(const i32x4*)((LB) + (H) * 8192 + (MI) * 1024 + aoff)
#define LDB8(DST, NI, H, LB) \
  DST = *(const i32x4*)((LB) + (H) * 16384 + (NI) * 1024 + boff)

#define MFMA16I()                                                           \
    __builtin_amdgcn_s_setprio(1);                                          \
    _Pragma("unroll") for (int _i = 0; _i < 4; ++_i)                        \
      _Pragma("unroll") for (int _n = 0; _n < 4; ++_n)                      \
        acc[_i][_n] = __builtin_amdgcn_mfma_i32_16x16x64_i8(                \
            a[_i], b[_n], acc[_i][_n], 0, 0, 0);                            \
    __builtin_amdgcn_s_setprio(0)

#define TILE2(T, CUR, OTH) do {                                             \
    i32x4 a[4], b[4];                                                       \
    /* ---- p1: h0 ---- */                                                  \
    _Pragma("unroll") for (int n = 0; n < 4; ++n) LDB8(b[n], n, 0, CUR);    \
    _Pragma("unroll") for (int i = 0; i < 4; ++i) LDA8(a[i], i, 0, CUR);    \
    STG_A((T) + 1, 1, OTH);                                                 \
    STG_B((T) + 1, 1, OTH);                                                 \
    PBAR; MFMA16I(); PBAR;                                                  \
    /* ---- p2: h1 ---- */                                                  \
    _Pragma("unroll") for (int n = 0; n < 4; ++n) LDB8(b[n], n, 1, CUR);    \
    _Pragma("unroll") for (int i = 0; i < 4; ++i) LDA8(a[i], i, 1, CUR);    \
    STG_A((T) + 2, 0, CUR);                                                 \
    STG_B((T) + 2, 0, CUR);                                                 \
    asm volatile("s_waitcnt vmcnt(3)" ::: "memory");                        \
    PBAR; MFMA16I(); PBAR;                                                  \
  } while (0)

__device__ __forceinline__ void gemm128x256_i8(const char* __restrict__ Ablk,
                                               const char* __restrict__ Bblk,
                                               char* lds, i32x4 acc[4][4]) {
  const int tid = threadIdx.x;
  const int wave = tid >> 6, lane = tid & 63;
  const int wm = (wave >> 2) * 64, wn = (wave & 3) * 64;
  const int lrow = lane & 15, q = lane >> 4;
  const int swz = ((q ^ (lrow & 3)) << 4);
  const int aoff = (wm + lrow) * 64 + swz;
  const int boff = 16384 + (wn + lrow) * 64 + swz;
  // per-lane pre-swizzled global staging source (row = wave*16 + lane/4)
  const int gsw = ((lane & 3) ^ ((lane >> 2) & 3)) << 4;
  const char* Asrc = Ablk + (size_t)(wave * 16 + (lane >> 2)) * DIMN + gsw;
  const char* Bsrc = Bblk + (size_t)(wave * 16 + (lane >> 2)) * DIMN + gsw;
  const int sdst = wave * 1024;  // wave-uniform LDS dest base (+lane*16 by HW)
  char* const L0 = lds;
  char* const L1 = lds + 49152;

  // prologue: tile0 both halves -> L0 (6 loads), tile1 h0 -> L1 (3 loads)
  STG_A(0, 0, L0); STG_B(0, 0, L0);
  STG_A(0, 1, L0); STG_B(0, 1, L0);
  STG_A(1, 0, L1); STG_B(1, 0, L1);
  asm volatile("s_waitcnt vmcnt(3)" ::: "memory");  // tile0 (6 oldest) landed
  __builtin_amdgcn_sched_barrier(0);
  __builtin_amdgcn_s_barrier();
  __builtin_amdgcn_sched_barrier(0);

  for (int t = 0; t < DIMN / 128; t += 2) {
    TILE2(t, L0, L1);
    TILE2(t + 1, L1, L0);
  }
}

#define ACC_INIT_F(acc)                                 \
  f32x4 acc[4][4];                                      \
  _Pragma("unroll") for (int _i = 0; _i < 4; ++_i)      \
      _Pragma("unroll") for (int _j = 0; _j < 4; ++_j)  \
          acc[_i][_j] = f32x4{0.f, 0.f, 0.f, 0.f};

#define ACC_INIT_I8(acc)                                \
  i32x4 acc[4][4];                                      \
  _Pragma("unroll") for (int _i = 0; _i < 4; ++_i)      \
      _Pragma("unroll") for (int _j = 0; _j < 4; ++_j)  \
          acc[_i][_j] = i32x4{0, 0, 0, 0};

#define EPI_COORDS                                      \
  const int lane = threadIdx.x & 63;                    \
  const int wave = threadIdx.x >> 6;                    \
  const int wm = (wave >> 1) * 64, wn = (wave & 1) * 64;\
  const int cq = (lane >> 4) * 4, cc = lane & 15;

#define EPI8_COORDS                                      \
  const int lane = threadIdx.x & 63;                     \
  const int wave = threadIdx.x >> 6;                     \
  const int wm = (wave >> 2) * 64, wn = (wave & 3) * 64; \
  const int cq = (lane >> 4) * 4, cc = lane & 15;

// ---------------- prep über-kernel: pack weights + quant x + zero caches ---
// blocks [0,16384): pack 4 weights int32->int8 (exact)
// blocks [16384,18432): x fp32 -> int8 + per-row scale
// blocks [18432,67584): zero cache rows >= 512 (8 regions x 24 MB)
__global__ __launch_bounds__(256) void k_prep(
    const int* __restrict__ q0, const int* __restrict__ q1,
    const int* __restrict__ q2, const int* __restrict__ q3,
    char* __restrict__ w8, const float* __restrict__ x,
    char* __restrict__ x8, float* __restrict__ xs,
    float* __restrict__ ck, float* __restrict__ cv) {
  __shared__ float red[4];
  const int bx = blockIdx.x;
  const int tid = threadIdx.x;
  if (bx < 16384) {
    const int w = bx >> 12;
    const int* q = (w == 0) ? q0 : (w == 1) ? q1 : (w == 2) ? q2 : q3;
    char* wp = w8 + (size_t)w * 16777216ull;
    size_t i = ((size_t)(bx & 4095) * 256 + tid) * 16;
    const i32x4* qp = (const i32x4*)(q + i);
    i32x4 a = qp[0], b = qp[1], c = qp[2], d = qp[3];
    i32x4 o;
    o[0] = (a[0] & 255) | ((a[1] & 255) << 8) | ((a[2] & 255) << 16) | (a[3] << 24);
    o[1] = (b[0] & 255) | ((b[1] & 255) << 8) | ((b[2] & 255) << 16) | (b[3] << 24);
    o[2] = (c[0] & 255) | ((c[1] & 255) << 8) | ((c[2] & 255) << 16) | (c[3] << 24);
    o[3] = (d[0] & 255) | ((d[1] & 255) << 8) | ((d[2] & 255) << 16) | (d[3] << 24);
    *(i32x4*)(wp + i) = o;
  } else if (bx < 18432) {
    const int row = bx - 16384;
    const float* src = x + (size_t)row * DIMN + tid * 16;
    f32x4 v[4];
#pragma unroll
    for (int j = 0; j < 4; ++j) v[j] = ((const f32x4*)src)[j];
    float am = 0.f;
#pragma unroll
    for (int j = 0; j < 4; ++j)
#pragma unroll
      for (int e = 0; e < 4; ++e) am = fmaxf(am, fabsf(v[j][e]));
#pragma unroll
    for (int off = 32; off; off >>= 1) am = fmaxf(am, __shfl_xor(am, off, 64));
    if ((tid & 63) == 0) red[tid >> 6] = am;
    __syncthreads();
    am = fmaxf(fmaxf(red[0], red[1]), fmaxf(red[2], red[3]));
    const float inv = am > 0.f ? 127.f / am : 0.f;
    i32x4 o;
#pragma unroll
    for (int j = 0; j < 4; ++j) {
      int b0 = (int)rintf(v[j][0] * inv), b1 = (int)rintf(v[j][1] * inv);
      int b2 = (int)rintf(v[j][2] * inv), b3 = (int)rintf(v[j][3] * inv);
      o[j] = (b0 & 255) | ((b1 & 255) << 8) | ((b2 & 255) << 16) | (b3 << 24);
    }
    *(i32x4*)(x8 + (size_t)row * DIMN + tid * 16) = o;
    if (tid == 0) xs[row] = am * (1.f / 127.f);
  } else {
    const int z = bx - 18432;
    const int region = z / 6144;  // 0..7: (b, ck/cv)
    const int zoff = z - region * 6144;
    const int b = region >> 1;
    float* base = (region & 1) ? cv : ck;
    char* p = (char*)(base + ((size_t)b * MAXSEQ + SEQ) * DIMN);
    *(f32x4*)(p + (size_t)zoff * 4096 + tid * 16) = f32x4{0.f, 0.f, 0.f, 0.f};
  }
}

// ---------------- attn bf16 -> int8, per-row absmax scale ------------------
__global__ __launch_bounds__(256) void k_quant_attn(const bf16* __restrict__ at,
                                                    char* __restrict__ a8,
                                                    float* __restrict__ as_) {
  __shared__ float red[4];
  const int row = blockIdx.x, tid = threadIdx.x;
  const bf16* src = at + (size_t)row * DIMN + tid * 16;
  bf16x8 h0 = ((const bf16x8*)src)[0], h1 = ((const bf16x8*)src)[1];
  float f[16];
#pragma unroll
  for (int j = 0; j < 8; ++j) { f[j] = (float)h0[j]; f[8 + j] = (float)h1[j]; }
  float am = 0.f;
#pragma unroll
  for (int j = 0; j < 16; ++j) am = fmaxf(am, fabsf(f[j]));
#pragma unroll
  for (int off = 32; off; off >>= 1) am = fmaxf(am, __shfl_xor(am, off, 64));
  if ((tid & 63) == 0) red[tid >> 6] = am;
  __syncthreads();
  am = fmaxf(fmaxf(red[0], red[1]), fmaxf(red[2], red[3]));
  const float inv = am > 0.f ? 127.f / am : 0.f;
  i32x4 o;
#pragma unroll
  for (int j = 0; j < 4; ++j) {
    int b0 = (int)rintf(f[j * 4 + 0] * inv), b1 = (int)rintf(f[j * 4 + 1] * inv);
    int b2 = (int)rintf(f[j * 4 + 2] * inv), b3 = (int)rintf(f[j * 4 + 3] * inv);
    o[j] = (b0 & 255) | ((b1 & 255) << 8) | ((b2 & 255) << 16) | (b3 << 24);
  }
  *(i32x4*)(a8 + (size_t)row * DIMN + tid * 16) = o;
  if (tid == 0) as_[row] = am * (1.f / 127.f);
}

// ---------------- QKV projection (i8, 128x256 2-phase) ---------------------
__global__ __launch_bounds__(512, 2) void k_gemm_qkv8(
    const char* __restrict__ X8, const char* __restrict__ W8,
    const float* __restrict__ xs, const float* __restrict__ sq,
    const float* __restrict__ sk, const float* __restrict__ sv,
    const float* __restrict__ fc, const float* __restrict__ fs,
    const int* __restrict__ idx, bf16* __restrict__ qbf,
    bf16* __restrict__ kbf, float* __restrict__ ck, float* __restrict__ cv) {
  __shared__ __align__(16) char lds[98304];
  const int n0 = blockIdx.x * 256;
  const int m0 = blockIdx.y * 128;
  const int z = blockIdx.z;
  const char* W = W8 + (size_t)z * 16777216ull;
  const float* sw = (z == 0) ? sq : (z == 1) ? sk : sv;
  ACC_INIT_I8(acc);
  gemm128x256_i8(X8 + (size_t)m0 * DIMN, W + (size_t)n0 * DIMN, lds, acc);
  EPI8_COORDS;
  if (z < 2) {
    bf16* dst = (z == 0) ? qbf : kbf;
#pragma unroll
    for (int mi = 0; mi < 4; ++mi)
#pragma unroll
      for (int ni = 0; ni < 4; ++ni)
#pragma unroll
        for (int r = 0; r < 4; ++r) {
          const int row = m0 + wm + mi * 16 + cq + r;
          const int col = n0 + wn + ni * 16 + cc;
          const float v = (float)acc[mi][ni][r] * xs[row] * sw[col];
          const float pv = __shfl_xor(v, 1, 64);  // partner col^1, same row
          const int s = row & 511, b = row >> 9;
          const int hd = col & 127, h = col >> 7;
          const int d2 = hd >> 1;
          const float c = fc[s * 64 + d2], sn = fs[s * 64 + d2];
          const float o = (col & 1) ? (pv * sn + v * c) : (v * c - pv * sn);
          dst[(((size_t)(b * NHEAD + h)) * SEQ + s) * HD + hd] = (bf16)o;
          if (z == 1) {
            const int pos = idx[s];
            ck[((size_t)b * MAXSEQ + pos) * DIMN + col] = o;
          }
        }
  } else {
#pragma unroll
    for (int mi = 0; mi < 4; ++mi)
#pragma unroll
      for (int ni = 0; ni < 4; ++ni)
#pragma unroll
        for (int r = 0; r < 4; ++r) {
          const int row = m0 + wm + mi * 16 + cq + r;
          const int col = n0 + wn + ni * 16 + cc;
          const int s = row & 511, b = row >> 9;
          cv[((size_t)b * MAXSEQ + s) * DIMN + col] =
              (float)acc[mi][ni][r] * xs[row] * sw[col];
        }
  }
}

// ---------------- V transpose: cache_v (b,s<512,h,d) fp32 -> (b,h,d,s) bf16
__global__ __launch_bounds__(256) void k_vt(const float* __restrict__ cv,
                                            bf16* __restrict__ vt) {
  __shared__ float tile[32][129];
  const int s0 = blockIdx.x * 32;
  const int bh = blockIdx.y;
  const int b = bh >> 5, h = bh & 31;
  const int tid = threadIdx.x;
  const float* src = cv + (size_t)b * MAXSEQ * DIMN + h * HD;
#pragma unroll
  for (int p = 0; p < 16; ++p) {
    const int row = p * 2 + (tid >> 7);
    const int d = tid & 127;
    tile[row][d] = src[(size_t)(s0 + row) * DIMN + d];
  }
  __syncthreads();
  bf16* dst = vt + (size_t)bh * HD * SEQ;
#pragma unroll
  for (int c = 0; c < 16; ++c) {
    const int d = c * 8 + (tid >> 5);
    const int sl = tid & 31;
    dst[(size_t)d * SEQ + s0 + sl] = (bf16)tile[sl][d];
  }
}

// ---------------- QK^T: packed causal grid, scores bf16 --------------------
__constant__ int g_tm[10] = {0, 1, 1, 2, 2, 2, 3, 3, 3, 3};
__constant__ int g_tn[10] = {0, 0, 1, 0, 1, 2, 0, 1, 2, 3};

__global__ __launch_bounds__(256, 2) void k_gemm_qk(
    const bf16* __restrict__ qb, const bf16* __restrict__ kb,
    bf16* __restrict__ sc) {
  const int m0 = g_tm[blockIdx.x] * BM;
  const int n0 = g_tn[blockIdx.x] * BN;
  const int bh = blockIdx.z;
  __shared__ __align__(16) bf16 As[BM * BK];
  __shared__ __align__(16) bf16 Bs[BN * BK];
  ACC_INIT_F(acc);
  gemm_core(qb + (size_t)bh * SEQ * HD + (size_t)m0 * HD,
            kb + (size_t)bh * SEQ * HD + (size_t)n0 * HD, HD, HD, HD, acc, As, Bs);
  EPI_COORDS;
  bf16* dst = sc + (size_t)bh * SEQ * SEQ;
#pragma unroll
  for (int mi = 0; mi < 4; ++mi)
#pragma unroll
    for (int ni = 0; ni < 4; ++ni)
#pragma unroll
      for (int r = 0; r < 4; ++r) {
        const int row = m0 + wm + mi * 16 + cq + r;
        const int col = n0 + wn + ni * 16 + cc;
        dst[(size_t)row * SEQ + col] = (bf16)(acc[mi][ni][r] * 0.08838834764831845f);
      }
}

// ---------------- row softmax, in-place ------------------------------------
__global__ __launch_bounds__(256) void k_softmax(bf16* __restrict__ sc) {
  const int row = blockIdx.x * 4 + (threadIdx.x >> 6);
  const int lane = threadIdx.x & 63;
  const int q = row & 511;
  bf16* p = sc + (size_t)row * SEQ + lane * 8;
  bf16x8 v8 = *(const bf16x8*)p;
  float lv[8];
  float m = -3.0e38f;
#pragma unroll
  for (int j = 0; j < 8; ++j) {
    const int kj = lane * 8 + j;
    lv[j] = (kj <= q) ? (float)v8[j] : -3.0e38f;
    m = fmaxf(m, lv[j]);
  }
#pragma unroll
  for (int off = 32; off; off >>= 1) m = fmaxf(m, __shfl_xor(m, off, 64));
  float e[8];
  float sum = 0.f;
#pragma unroll
  for (int j = 0; j < 8; ++j) {
    e[j] = (lane * 8 + j <= q) ? __expf(lv[j] - m) : 0.f;
    sum += e[j];
  }
#pragma unroll
  for (int off = 32; off; off >>= 1) sum += __shfl_xor(sum, off, 64);
  const float r = 1.f / sum;
  bf16x8 o;
#pragma unroll
  for (int j = 0; j < 8; ++j) o[j] = (bf16)(e[j] * r);
  *(bf16x8*)p = o;
}

// ---------------- P @ V, causal K-bound ------------------------------------
__global__ __launch_bounds__(256, 2) void k_gemm_pv(
    const bf16* __restrict__ P, const bf16* __restrict__ vt,
    bf16* __restrict__ attn) {
  const int m0 = blockIdx.y * BM;
  const int bh = blockIdx.z;
  const int kmax = m0 + BM;
  __shared__ __align__(16) bf16 As[BM * BK];
  __shared__ __align__(16) bf16 Bs[BN * BK];
  ACC_INIT_F(acc);
  gemm_core(P + (size_t)bh * SEQ * SEQ + (size_t)m0 * SEQ,
            vt + (size_t)bh * HD * SEQ, SEQ, SEQ, kmax, acc, As, Bs);
  EPI_COORDS;
  const int b = bh >> 5, h = bh & 31;
#pragma unroll
  for (int mi = 0; mi < 4; ++mi)
#pragma unroll
    for (int ni = 0; ni < 4; ++ni)
#pragma unroll
      for (int r = 0; r < 4; ++r) {
        const int row = m0 + wm + mi * 16 + cq + r;
        const int col = wn + ni * 16 + cc;  // < 128
        attn[((size_t)(b * SEQ + row)) * DIMN + h * HD + col] = (bf16)acc[mi][ni][r];
      }
}

// ---------------- output projection (i8, 128x256 2-phase) ------------------
__global__ __launch_bounds__(512, 2) void k_gemm_out8(
    const char* __restrict__ A8, const char* __restrict__ WO8,
    const float* __restrict__ as_, const float* __restrict__ so,
    float* __restrict__ out) {
  __shared__ __align__(16) char lds[98304];
  const int n0 = blockIdx.x * 256;
  const int m0 = blockIdx.y * 128;
  ACC_INIT_I8(acc);
  gemm128x256_i8(A8 + (size_t)m0 * DIMN, WO8 + (size_t)n0 * DIMN, lds, acc);
  EPI8_COORDS;
#pragma unroll
  for (int mi = 0; mi < 4; ++mi)
#pragma unroll
    for (int ni = 0; ni < 4; ++ni)
#pragma unroll
      for (int r = 0; r < 4; ++r) {
        const int row = m0 + wm + mi * 16 + cq + r;
        const int col = n0 + wn + ni * 16 + cc;
        out[(size_t)row * DIMN + col] = (float)acc[mi][ni][r] * as_[row] * so[col];
      }
}

// ===========================================================================
extern "C" void kernel_launch(void* const* d_in, const int* in_sizes, int n_in,
                              void* d_out, int out_size, void* d_ws, size_t ws_size,
                              hipStream_t stream) {
  const float* x = (const float*)d_in[0];
  const float* fc = (const float*)d_in[1];
  const float* fs = (const float*)d_in[2];
  const int* idx = (const int*)d_in[4];
  const int* wq_q = (const int*)d_in[7];
  const int* wk_q = (const int*)d_in[9];
  const int* wv_q = (const int*)d_in[11];
  const int* wo_q = (const int*)d_in[13];
  const float* wq_s = (const float*)d_in[8];
  const float* wk_s = (const float*)d_in[10];
  const float* wv_s = (const float*)d_in[12];
  const float* wo_s = (const float*)d_in[14];

  float* out = (float*)d_out;                 // (4,512,4096) fp32
  float* ck_out = out + 8388608;              // (4,2048,32,128) fp32
  float* cv_out = ck_out + 33554432;          // (4,2048,32,128) fp32

  // workspace layout (~230 MiB; harness ws is ~1.15 GiB per poison fills)
  char* ws = (char*)d_ws;
  char* W8   = ws;                            // 64 MiB: WQ8,WK8,WV8,WO8
  char* X8   = ws + 67108864ull;              // 8.4 MiB
  float* XS  = (float*)(ws + 75497472ull);    // 2048 f
  float* AS  = (float*)(ws + 75513856ull);    // 2048 f
  bf16* QBF  = (bf16*)(ws + 83886080ull);     // (b,h,s,d) 16.8 MiB
  bf16* KBF  = (bf16*)(ws + 100663296ull);
  bf16* VTB  = (bf16*)(ws + 117440512ull);    // (b,h,d,s)
  bf16* ATTN = (bf16*)(ws + 134217728ull);
  char* A8   = ws + 150994944ull;             // 8.4 MiB
  bf16* SC   = (bf16*)(ws + 167772160ull);    // 64 MiB scores

  // 1. prep: pack weights (exact), quant x, zero cache rows >= 512
  k_prep<<<dim3(67584), 256, 0, stream>>>(wq_q, wk_q, wv_q, wo_q, W8, x, X8, XS,
                                          ck_out, cv_out);
  // 2. QKV projections (i8, 128x256 2-phase), fused dequant+rotary epilogue
  //    768 blocks = 3 exact rounds of 256 CUs at 1 block/CU
  k_gemm_qkv8<<<dim3(16, 16, 3), 512, 0, stream>>>(
      X8, W8, XS, wq_s, wk_s, wv_s, fc, fs, idx, QBF, KBF, ck_out, cv_out);
  // 3. V^T bf16 (b,h,d,s)
  k_vt<<<dim3(16, 128), 256, 0, stream>>>(cv_out, VTB);
  // 4. attention
  k_gemm_qk<<<dim3(10, 1, 128), 256, 0, stream>>>(QBF, KBF, SC);
  k_softmax<<<dim3(16384), 256, 0, stream>>>(SC);
  k_gemm_pv<<<dim3(1, 4, 128), 256, 0, stream>>>(SC, VTB, ATTN);
  // 5. attn -> int8, output projection (i8, 128x256 2-phase; 256 blocks = 1 round)
  k_quant_attn<<<dim3(2048), 256, 0, stream>>>(ATTN, A8, AS);
  k_gemm_out8<<<dim3(16, 16), 512, 0, stream>>>(A8, W8 + 50331648ull, AS, wo_s, out);
  (void)in_sizes; (void)n_in; (void)out_size; (void)ws_size;
}

// Round 9
// 866.537 us; speedup vs baseline: 1.0446x; 1.0446x over previous
//
#include <hip/hip_runtime.h>
#include <cstdint>
#include <cstddef>

typedef __bf16 bf16;
typedef __attribute__((ext_vector_type(8))) __bf16 bf16x8;
typedef __attribute__((ext_vector_type(2))) __bf16 bf16x2;
typedef __attribute__((ext_vector_type(4))) float f32x4;
typedef __attribute__((ext_vector_type(2))) float f32x2;
typedef __attribute__((ext_vector_type(4))) int i32x4;

#define DIMN 4096
#define SEQ 512
#define MAXSEQ 2048
#define NHEAD 32
#define HD 128

#define BM 128
#define BN 128
#define BK 32    // bf16 core: 32 elems = 64 B rows

// ---------------- async global->LDS (wave-uniform base + lane*16) ----------
__device__ __forceinline__ void gld_lds16(const void* g, void* l) {
  __builtin_amdgcn_global_load_lds(
      (const __attribute__((address_space(1))) unsigned int*)g,
      (__attribute__((address_space(3))) unsigned int*)l, 16, 0, 0);
}

// ---------------- bf16 bt-GEMM core (m97 lineage, proven) ------------------
__device__ __forceinline__ void gemm_core(const bf16* Ablk, const bf16* Bblk,
                                          int lda, int ldb, int kmax,
                                          f32x4 acc[4][4], bf16* As, bf16* Bs) {
  const int tid = threadIdx.x;
  const int wave = tid >> 6;
  const int lane = tid & 63;
  const int wm = (wave >> 1) * 64;
  const int wn = (wave & 1) * 64;
  const int lrow = lane & 15;
  const int lkq8 = (lane >> 4) * 8;
  const int srow = wave * 32 + (lane >> 2);
  const int scol = (lane & 3) * 8;
  const bf16* Ag = Ablk + (size_t)srow * lda + scol;
  const bf16* Bg = Bblk + (size_t)srow * ldb + scol;
  bf16* lA = As + wave * 32 * BK;
  bf16* lB = Bs + wave * 32 * BK;

  for (int k0 = 0; k0 < kmax; k0 += BK) {
    __syncthreads();
    gld_lds16(Ag + k0, lA);
    gld_lds16(Ag + k0 + (size_t)16 * lda, lA + 16 * BK);
    gld_lds16(Bg + k0, lB);
    gld_lds16(Bg + k0 + (size_t)16 * ldb, lB + 16 * BK);
    __syncthreads();
    bf16x8 a[4], b[4];
#pragma unroll
    for (int i = 0; i < 4; ++i)
      a[i] = *(const bf16x8*)(As + (wm + i * 16 + lrow) * BK + lkq8);
#pragma unroll
    for (int i = 0; i < 4; ++i)
      b[i] = *(const bf16x8*)(Bs + (wn + i * 16 + lrow) * BK + lkq8);
#pragma unroll
    for (int mi = 0; mi < 4; ++mi)
#pragma unroll
      for (int ni = 0; ni < 4; ++ni)
        acc[mi][ni] = __builtin_amdgcn_mfma_f32_16x16x32_bf16(a[mi], b[ni], acc[mi][ni], 0, 0, 0);
  }
}

// ===========================================================================
// int8 128x256 tile, 3-buffer prefetch-2, full-8 XOR swizzle (round-8)
//
// Round-7 counters: MfmaUtil 23%, BANK_CONFLICT 12.6M, occupancy at 1-blk/CU
// cap, vmcnt depth 1 phase. Fixes, schedule otherwise identical:
//  (a) rows now full K-tile = 128 B (8 granules); LDS granule g of row r
//      holds global granule g^(r&7) (pre-swizzled global src, linear dest;
//      frag ds_read_b128 at g=(h*4+q)^(lrow&7)). Every 8-lane group hits
//      8 distinct granules -> all 32 banks once -> ~0 conflicts.
//  (b) 3 LDS buffers (144 KiB), tile t stages tile t+2; per-tile vmcnt(6)
//      waits on loads issued 4 phases (~2600 cy) earlier -> wait ~ 0.
// Per K-tile t (C = buf t%3, S = buf (t+2)%3; 6 chunk-loads/tile, 3+3):
//   p1: ds_read h0 frags | stage 3 chunks(t+2)->S | bar | 16 MFMA | bar
//   p2: ds_read h1 frags | stage 3 chunks(t+2)->S | vmcnt(6) | bar | 16 MFMA | bar
// Race-free: buffer S holds tile t-1, fully consumed before the barrier
// pair ending t-1; stores of t p1/p2 are program-ordered after it. vmcnt(6)
// at t p2 retires exactly tile t+1's 6 loads (issued during t-1), leaving
// t+2's 6 in flight. Tail stages (t+2>=32) read a few KB past the operand
// into adjacent mapped ws and land in dead LDS buffers -> harmless.
// ===========================================================================

#define PBAR do {                              \
    asm volatile("" ::: "memory");             \
    __builtin_amdgcn_sched_barrier(0);         \
    __builtin_amdgcn_s_barrier();              \
    __builtin_amdgcn_sched_barrier(0);         \
    asm volatile("" ::: "memory");             \
  } while (0)

// chunk = 64 rows x 128 B = 8 KB = one block-wide gld_lds (512 x 16 B)
#define STG_A(KT, C, LB) \
  gld_lds16(Asrc + (KT) * 128 + (size_t)(C) * 64 * DIMN, (LB) + (C) * 8192 + sdst)
#define STG_B(KT, C, LB) \
  gld_lds16(Bsrc + (KT) * 128 + (size_t)(C) * 64 * DIMN, (LB) + 16384 + (C) * 8192 + sdst)

#define LDA8(DST, MI, H, LB) \
  DST = *(const i32x4*)((LB) + (MI) * 2048 + aoff + ((H) ? g1off : g0off))
#define LDB8(DST, NI, H, LB) \
  DST = *(const i32x4*)((LB) + 16384 + (NI) * 2048 + boff + ((H) ? g1off : g0off))

#define MFMA16I()                                                           \
    __builtin_amdgcn_s_setprio(1);                                          \
    _Pragma("unroll") for (int _i = 0; _i < 4; ++_i)                        \
      _Pragma("unroll") for (int _n = 0; _n < 4; ++_n)                      \
        acc[_i][_n] = __builtin_amdgcn_mfma_i32_16x16x64_i8(                \
            a[_i], b[_n], acc[_i][_n], 0, 0, 0);                            \
    __builtin_amdgcn_s_setprio(0)

#define TILE3(T, CUR, STG) do {                                             \
    i32x4 a[4], b[4];                                                       \
    /* ---- p1: h0 ---- */                                                  \
    _Pragma("unroll") for (int n = 0; n < 4; ++n) LDB8(b[n], n, 0, CUR);    \
    _Pragma("unroll") for (int i = 0; i < 4; ++i) LDA8(a[i], i, 0, CUR);    \
    STG_B((T) + 2, 0, STG);                                                 \
    STG_B((T) + 2, 1, STG);                                                 \
    STG_A((T) + 2, 0, STG);                                                 \
    PBAR; MFMA16I(); PBAR;                                                  \
    /* ---- p2: h1 ---- */                                                  \
    _Pragma("unroll") for (int n = 0; n < 4; ++n) LDB8(b[n], n, 1, CUR);    \
    _Pragma("unroll") for (int i = 0; i < 4; ++i) LDA8(a[i], i, 1, CUR);    \
    STG_B((T) + 2, 2, STG);                                                 \
    STG_B((T) + 2, 3, STG);                                                 \
    STG_A((T) + 2, 1, STG);                                                 \
    asm volatile("s_waitcnt vmcnt(6)" ::: "memory");                        \
    PBAR; MFMA16I(); PBAR;                                                  \
  } while (0)

__device__ __forceinline__ void gemm128x256_i8(const char* __restrict__ Ablk,
                                               const char* __restrict__ Bblk,
                                               char* lds, i32x4 acc[4][4]) {
  const int tid = threadIdx.x;
  const int wave = tid >> 6, lane = tid & 63;
  const int wm = (wave >> 2) * 64, wn = (wave & 3) * 64;
  const int lrow = lane & 15, q = lane >> 4;
  // frag-read granule = ((h*4+q) ^ (lrow&7)) = ((h^hbit)<<2) | (q^(lrow&3))
  const int qx = q ^ (lrow & 3);
  const int hbit = (lrow >> 2) & 1;
  const int g0off = (((hbit) << 2) | qx) << 4;
  const int g1off = (((hbit ^ 1) << 2) | qx) << 4;
  const int aoff = (wm + lrow) * 128;
  const int boff = (wn + lrow) * 128;
  // staging: lane covers LDS (row = wave*8 + lane/8, granule = lane&7);
  // global granule = (lane&7) ^ (lane>>3) = g ^ (row&7)
  const int gsw = ((lane & 7) ^ (lane >> 3)) << 4;
  const char* Asrc = Ablk + (size_t)(wave * 8 + (lane >> 3)) * DIMN + gsw;
  const char* Bsrc = Bblk + (size_t)(wave * 8 + (lane >> 3)) * DIMN + gsw;
  const int sdst = wave * 1024;  // wave-uniform LDS dest base (+lane*16 by HW)
  char* const L0 = lds;
  char* const L1 = lds + 49152;
  char* const L2 = lds + 98304;

  // prologue: t0 -> L0 (6 loads), t1 -> L1 (6 loads)
  STG_A(0, 0, L0); STG_A(0, 1, L0);
  STG_B(0, 0, L0); STG_B(0, 1, L0); STG_B(0, 2, L0); STG_B(0, 3, L0);
  STG_A(1, 0, L1); STG_A(1, 1, L1);
  STG_B(1, 0, L1); STG_B(1, 1, L1); STG_B(1, 2, L1); STG_B(1, 3, L1);
  asm volatile("s_waitcnt vmcnt(6)" ::: "memory");  // t0 (6 oldest) landed
  __builtin_amdgcn_sched_barrier(0);
  __builtin_amdgcn_s_barrier();
  __builtin_amdgcn_sched_barrier(0);

  for (int t = 0; t < 30; t += 3) {
    TILE3(t, L0, L2);
    TILE3(t + 1, L1, L0);
    TILE3(t + 2, L2, L1);
  }
  TILE3(30, L0, L2);   // stages t=32 (garbage, dead buffer) -- harmless
  TILE3(31, L1, L0);   // stages t=33 (garbage, dead buffer) -- harmless
}

#define ACC_INIT_F(acc)                                 \
  f32x4 acc[4][4];                                      \
  _Pragma("unroll") for (int _i = 0; _i < 4; ++_i)      \
      _Pragma("unroll") for (int _j = 0; _j < 4; ++_j)  \
          acc[_i][_j] = f32x4{0.f, 0.f, 0.f, 0.f};

#define ACC_INIT_I8(acc)                                \
  i32x4 acc[4][4];                                      \
  _Pragma("unroll") for (int _i = 0; _i < 4; ++_i)      \
      _Pragma("unroll") for (int _j = 0; _j < 4; ++_j)  \
          acc[_i][_j] = i32x4{0, 0, 0, 0};

#define EPI_COORDS                                      \
  const int lane = threadIdx.x & 63;                    \
  const int wave = threadIdx.x >> 6;                    \
  const int wm = (wave >> 1) * 64, wn = (wave & 1) * 64;\
  const int cq = (lane >> 4) * 4, cc = lane & 15;

#define EPI8_COORDS                                      \
  const int lane = threadIdx.x & 63;                     \
  const int wave = threadIdx.x >> 6;                     \
  const int wm = (wave >> 2) * 64, wn = (wave & 3) * 64; \
  const int cq = (lane >> 4) * 4, cc = lane & 15;

// ---------------- prep über-kernel: pack weights + quant x + zero caches ---
// blocks [0,16384): pack 4 weights int32->int8 (exact)
// blocks [16384,18432): x fp32 -> int8 + per-row scale
// blocks [18432,67584): zero cache rows >= 512 (8 regions x 24 MB)
__global__ __launch_bounds__(256) void k_prep(
    const int* __restrict__ q0, const int* __restrict__ q1,
    const int* __restrict__ q2, const int* __restrict__ q3,
    char* __restrict__ w8, const float* __restrict__ x,
    char* __restrict__ x8, float* __restrict__ xs,
    float* __restrict__ ck, float* __restrict__ cv) {
  __shared__ float red[4];
  const int bx = blockIdx.x;
  const int tid = threadIdx.x;
  if (bx < 16384) {
    const int w = bx >> 12;
    const int* q = (w == 0) ? q0 : (w == 1) ? q1 : (w == 2) ? q2 : q3;
    char* wp = w8 + (size_t)w * 16777216ull;
    size_t i = ((size_t)(bx & 4095) * 256 + tid) * 16;
    const i32x4* qp = (const i32x4*)(q + i);
    i32x4 a = qp[0], b = qp[1], c = qp[2], d = qp[3];
    i32x4 o;
    o[0] = (a[0] & 255) | ((a[1] & 255) << 8) | ((a[2] & 255) << 16) | (a[3] << 24);
    o[1] = (b[0] & 255) | ((b[1] & 255) << 8) | ((b[2] & 255) << 16) | (b[3] << 24);
    o[2] = (c[0] & 255) | ((c[1] & 255) << 8) | ((c[2] & 255) << 16) | (c[3] << 24);
    o[3] = (d[0] & 255) | ((d[1] & 255) << 8) | ((d[2] & 255) << 16) | (d[3] << 24);
    *(i32x4*)(wp + i) = o;
  } else if (bx < 18432) {
    const int row = bx - 16384;
    const float* src = x + (size_t)row * DIMN + tid * 16;
    f32x4 v[4];
#pragma unroll
    for (int j = 0; j < 4; ++j) v[j] = ((const f32x4*)src)[j];
    float am = 0.f;
#pragma unroll
    for (int j = 0; j < 4; ++j)
#pragma unroll
      for (int e = 0; e < 4; ++e) am = fmaxf(am, fabsf(v[j][e]));
#pragma unroll
    for (int off = 32; off; off >>= 1) am = fmaxf(am, __shfl_xor(am, off, 64));
    if ((tid & 63) == 0) red[tid >> 6] = am;
    __syncthreads();
    am = fmaxf(fmaxf(red[0], red[1]), fmaxf(red[2], red[3]));
    const float inv = am > 0.f ? 127.f / am : 0.f;
    i32x4 o;
#pragma unroll
    for (int j = 0; j < 4; ++j) {
      int b0 = (int)rintf(v[j][0] * inv), b1 = (int)rintf(v[j][1] * inv);
      int b2 = (int)rintf(v[j][2] * inv), b3 = (int)rintf(v[j][3] * inv);
      o[j] = (b0 & 255) | ((b1 & 255) << 8) | ((b2 & 255) << 16) | (b3 << 24);
    }
    *(i32x4*)(x8 + (size_t)row * DIMN + tid * 16) = o;
    if (tid == 0) xs[row] = am * (1.f / 127.f);
  } else {
    const int z = bx - 18432;
    const int region = z / 6144;  // 0..7: (b, ck/cv)
    const int zoff = z - region * 6144;
    const int b = region >> 1;
    float* base = (region & 1) ? cv : ck;
    char* p = (char*)(base + ((size_t)b * MAXSEQ + SEQ) * DIMN);
    *(f32x4*)(p + (size_t)zoff * 4096 + tid * 16) = f32x4{0.f, 0.f, 0.f, 0.f};
  }
}

// ---------------- attn bf16 -> int8, per-row absmax scale ------------------
__global__ __launch_bounds__(256) void k_quant_attn(const bf16* __restrict__ at,
                                                    char* __restrict__ a8,
                                                    float* __restrict__ as_) {
  __shared__ float red[4];
  const int row = blockIdx.x, tid = threadIdx.x;
  const bf16* src = at + (size_t)row * DIMN + tid * 16;
  bf16x8 h0 = ((const bf16x8*)src)[0], h1 = ((const bf16x8*)src)[1];
  float f[16];
#pragma unroll
  for (int j = 0; j < 8; ++j) { f[j] = (float)h0[j]; f[8 + j] = (float)h1[j]; }
  float am = 0.f;
#pragma unroll
  for (int j = 0; j < 16; ++j) am = fmaxf(am, fabsf(f[j]));
#pragma unroll
  for (int off = 32; off; off >>= 1) am = fmaxf(am, __shfl_xor(am, off, 64));
  if ((tid & 63) == 0) red[tid >> 6] = am;
  __syncthreads();
  am = fmaxf(fmaxf(red[0], red[1]), fmaxf(red[2], red[3]));
  const float inv = am > 0.f ? 127.f / am : 0.f;
  i32x4 o;
#pragma unroll
  for (int j = 0; j < 4; ++j) {
    int b0 = (int)rintf(f[j * 4 + 0] * inv), b1 = (int)rintf(f[j * 4 + 1] * inv);
    int b2 = (int)rintf(f[j * 4 + 2] * inv), b3 = (int)rintf(f[j * 4 + 3] * inv);
    o[j] = (b0 & 255) | ((b1 & 255) << 8) | ((b2 & 255) << 16) | (b3 << 24);
  }
  *(i32x4*)(a8 + (size_t)row * DIMN + tid * 16) = o;
  if (tid == 0) as_[row] = am * (1.f / 127.f);
}

// ---------------- QKV projection (i8, 128x256 3-buf) -----------------------
__global__ __launch_bounds__(512, 2) void k_gemm_qkv8(
    const char* __restrict__ X8, const char* __restrict__ W8,
    const float* __restrict__ xs, const float* __restrict__ sq,
    const float* __restrict__ sk, const float* __restrict__ sv,
    const float* __restrict__ fc, const float* __restrict__ fs,
    const int* __restrict__ idx, bf16* __restrict__ qbf,
    bf16* __restrict__ kbf, float* __restrict__ ck, float* __restrict__ cv) {
  __shared__ __align__(16) char lds[147456];
  const int n0 = blockIdx.x * 256;
  const int m0 = blockIdx.y * 128;
  const int z = blockIdx.z;
  const char* W = W8 + (size_t)z * 16777216ull;
  const float* sw = (z == 0) ? sq : (z == 1) ? sk : sv;
  ACC_INIT_I8(acc);
  gemm128x256_i8(X8 + (size_t)m0 * DIMN, W + (size_t)n0 * DIMN, lds, acc);
  EPI8_COORDS;
  if (z < 2) {
    bf16* dst = (z == 0) ? qbf : kbf;
#pragma unroll
    for (int mi = 0; mi < 4; ++mi)
#pragma unroll
      for (int ni = 0; ni < 4; ++ni)
#pragma unroll
        for (int r = 0; r < 4; ++r) {
          const int row = m0 + wm + mi * 16 + cq + r;
          const int col = n0 + wn + ni * 16 + cc;
          const float v = (float)acc[mi][ni][r] * xs[row] * sw[col];
          const float pv = __shfl_xor(v, 1, 64);  // partner col^1, same row
          const int s = row & 511, b = row >> 9;
          const int hd = col & 127, h = col >> 7;
          const int d2 = hd >> 1;
          const float c = fc[s * 64 + d2], sn = fs[s * 64 + d2];
          const float o = (col & 1) ? (pv * sn + v * c) : (v * c - pv * sn);
          dst[(((size_t)(b * NHEAD + h)) * SEQ + s) * HD + hd] = (bf16)o;
          if (z == 1) {
            const int pos = idx[s];
            ck[((size_t)b * MAXSEQ + pos) * DIMN + col] = o;
          }
        }
  } else {
#pragma unroll
    for (int mi = 0; mi < 4; ++mi)
#pragma unroll
      for (int ni = 0; ni < 4; ++ni)
#pragma unroll
        for (int r = 0; r < 4; ++r) {
          const int row = m0 + wm + mi * 16 + cq + r;
          const int col = n0 + wn + ni * 16 + cc;
          const int s = row & 511, b = row >> 9;
          cv[((size_t)b * MAXSEQ + s) * DIMN + col] =
              (float)acc[mi][ni][r] * xs[row] * sw[col];
        }
  }
}

// ---------------- V transpose: cache_v (b,s<512,h,d) fp32 -> (b,h,d,s) bf16
__global__ __launch_bounds__(256) void k_vt(const float* __restrict__ cv,
                                            bf16* __restrict__ vt) {
  __shared__ float tile[32][129];
  const int s0 = blockIdx.x * 32;
  const int bh = blockIdx.y;
  const int b = bh >> 5, h = bh & 31;
  const int tid = threadIdx.x;
  const float* src = cv + (size_t)b * MAXSEQ * DIMN + h * HD;
#pragma unroll
  for (int p = 0; p < 16; ++p) {
    const int row = p * 2 + (tid >> 7);
    const int d = tid & 127;
    tile[row][d] = src[(size_t)(s0 + row) * DIMN + d];
  }
  __syncthreads();
  bf16* dst = vt + (size_t)bh * HD * SEQ;
#pragma unroll
  for (int c = 0; c < 16; ++c) {
    const int d = c * 8 + (tid >> 5);
    const int sl = tid & 31;
    dst[(size_t)d * SEQ + s0 + sl] = (bf16)tile[sl][d];
  }
}

// ---------------- QK^T: packed causal grid, scores bf16 --------------------
__constant__ int g_tm[10] = {0, 1, 1, 2, 2, 2, 3, 3, 3, 3};
__constant__ int g_tn[10] = {0, 0, 1, 0, 1, 2, 0, 1, 2, 3};

__global__ __launch_bounds__(256, 2) void k_gemm_qk(
    const bf16* __restrict__ qb, const bf16* __restrict__ kb,
    bf16* __restrict__ sc) {
  const int m0 = g_tm[blockIdx.x] * BM;
  const int n0 = g_tn[blockIdx.x] * BN;
  const int bh = blockIdx.z;
  __shared__ __align__(16) bf16 As[BM * BK];
  __shared__ __align__(16) bf16 Bs[BN * BK];
  ACC_INIT_F(acc);
  gemm_core(qb + (size_t)bh * SEQ * HD + (size_t)m0 * HD,
            kb + (size_t)bh * SEQ * HD + (size_t)n0 * HD, HD, HD, HD, acc, As, Bs);
  EPI_COORDS;
  bf16* dst = sc + (size_t)bh * SEQ * SEQ;
#pragma unroll
  for (int mi = 0; mi < 4; ++mi)
#pragma unroll
    for (int ni = 0; ni < 4; ++ni)
#pragma unroll
      for (int r = 0; r < 4; ++r) {
        const int row = m0 + wm + mi * 16 + cq + r;
        const int col = n0 + wn + ni * 16 + cc;
        dst[(size_t)row * SEQ + col] = (bf16)(acc[mi][ni][r] * 0.08838834764831845f);
      }
}

// ---------------- row softmax, in-place ------------------------------------
__global__ __launch_bounds__(256) void k_softmax(bf16* __restrict__ sc) {
  const int row = blockIdx.x * 4 + (threadIdx.x >> 6);
  const int lane = threadIdx.x & 63;
  const int q = row & 511;
  bf16* p = sc + (size_t)row * SEQ + lane * 8;
  bf16x8 v8 = *(const bf16x8*)p;
  float lv[8];
  float m = -3.0e38f;
#pragma unroll
  for (int j = 0; j < 8; ++j) {
    const int kj = lane * 8 + j;
    lv[j] = (kj <= q) ? (float)v8[j] : -3.0e38f;
    m = fmaxf(m, lv[j]);
  }
#pragma unroll
  for (int off = 32; off; off >>= 1) m = fmaxf(m, __shfl_xor(m, off, 64));
  float e[8];
  float sum = 0.f;
#pragma unroll
  for (int j = 0; j < 8; ++j) {
    e[j] = (lane * 8 + j <= q) ? __expf(lv[j] - m) : 0.f;
    sum += e[j];
  }
#pragma unroll
  for (int off = 32; off; off >>= 1) sum += __shfl_xor(sum, off, 64);
  const float r = 1.f / sum;
  bf16x8 o;
#pragma unroll
  for (int j = 0; j < 8; ++j) o[j] = (bf16)(e[j] * r);
  *(bf16x8*)p = o;
}

// ---------------- P @ V, causal K-bound ------------------------------------
__global__ __launch_bounds__(256, 2) void k_gemm_pv(
    const bf16* __restrict__ P, const bf16* __restrict__ vt,
    bf16* __restrict__ attn) {
  const int m0 = blockIdx.y * BM;
  const int bh = blockIdx.z;
  const int kmax = m0 + BM;
  __shared__ __align__(16) bf16 As[BM * BK];
  __shared__ __align__(16) bf16 Bs[BN * BK];
  ACC_INIT_F(acc);
  gemm_core(P + (size_t)bh * SEQ * SEQ + (size_t)m0 * SEQ,
            vt + (size_t)bh * HD * SEQ, SEQ, SEQ, kmax, acc, As, Bs);
  EPI_COORDS;
  const int b = bh >> 5, h = bh & 31;
#pragma unroll
  for (int mi = 0; mi < 4; ++mi)
#pragma unroll
    for (int ni = 0; ni < 4; ++ni)
#pragma unroll
      for (int r = 0; r < 4; ++r) {
        const int row = m0 + wm + mi * 16 + cq + r;
        const int col = wn + ni * 16 + cc;  // < 128
        attn[((size_t)(b * SEQ + row)) * DIMN + h * HD + col] = (bf16)acc[mi][ni][r];
      }
}

// ---------------- output projection (i8, 128x256 3-buf) --------------------
__global__ __launch_bounds__(512, 2) void k_gemm_out8(
    const char* __restrict__ A8, const char* __restrict__ WO8,
    const float* __restrict__ as_, const float* __restrict__ so,
    float* __restrict__ out) {
  __shared__ __align__(16) char lds[147456];
  const int n0 = blockIdx.x * 256;
  const int m0 = blockIdx.y * 128;
  ACC_INIT_I8(acc);
  gemm128x256_i8(A8 + (size_t)m0 * DIMN, WO8 + (size_t)n0 * DIMN, lds, acc);
  EPI8_COORDS;
#pragma unroll
  for (int mi = 0; mi < 4; ++mi)
#pragma unroll
    for (int ni = 0; ni < 4; ++ni)
#pragma unroll
      for (int r = 0; r < 4; ++r) {
        const int row = m0 + wm + mi * 16 + cq + r;
        const int col = n0 + wn + ni * 16 + cc;
        out[(size_t)row * DIMN + col] = (float)acc[mi][ni][r] * as_[row] * so[col];
      }
}

// ===========================================================================
extern "C" void kernel_launch(void* const* d_in, const int* in_sizes, int n_in,
                              void* d_out, int out_size, void* d_ws, size_t ws_size,
                              hipStream_t stream) {
  const float* x = (const float*)d_in[0];
  const float* fc = (const float*)d_in[1];
  const float* fs = (const float*)d_in[2];
  const int* idx = (const int*)d_in[4];
  const int* wq_q = (const int*)d_in[7];
  const int* wk_q = (const int*)d_in[9];
  const int* wv_q = (const int*)d_in[11];
  const int* wo_q = (const int*)d_in[13];
  const float* wq_s = (const float*)d_in[8];
  const float* wk_s = (const float*)d_in[10];
  const float* wv_s = (const float*)d_in[12];
  const float* wo_s = (const float*)d_in[14];

  float* out = (float*)d_out;                 // (4,512,4096) fp32
  float* ck_out = out + 8388608;              // (4,2048,32,128) fp32
  float* cv_out = ck_out + 33554432;          // (4,2048,32,128) fp32

  // workspace layout (~230 MiB; harness ws is ~1.15 GiB per poison fills)
  char* ws = (char*)d_ws;
  char* W8   = ws;                            // 64 MiB: WQ8,WK8,WV8,WO8
  char* X8   = ws + 67108864ull;              // 8.4 MiB
  float* XS  = (float*)(ws + 75497472ull);    // 2048 f
  float* AS  = (float*)(ws + 75513856ull);    // 2048 f
  bf16* QBF  = (bf16*)(ws + 83886080ull);     // (b,h,s,d) 16.8 MiB
  bf16* KBF  = (bf16*)(ws + 100663296ull);
  bf16* VTB  = (bf16*)(ws + 117440512ull);    // (b,h,d,s)
  bf16* ATTN = (bf16*)(ws + 134217728ull);
  char* A8   = ws + 150994944ull;             // 8.4 MiB
  bf16* SC   = (bf16*)(ws + 167772160ull);    // 64 MiB scores

  // 1. prep: pack weights (exact), quant x, zero cache rows >= 512
  k_prep<<<dim3(67584), 256, 0, stream>>>(wq_q, wk_q, wv_q, wo_q, W8, x, X8, XS,
                                          ck_out, cv_out);
  // 2. QKV projections (i8, 128x256 3-buf), fused dequant+rotary epilogue
  //    768 blocks = 3 exact rounds of 256 CUs at 1 block/CU
  k_gemm_qkv8<<<dim3(16, 16, 3), 512, 0, stream>>>(
      X8, W8, XS, wq_s, wk_s, wv_s, fc, fs, idx, QBF, KBF, ck_out, cv_out);
  // 3. V^T bf16 (b,h,d,s)
  k_vt<<<dim3(16, 128), 256, 0, stream>>>(cv_out, VTB);
  // 4. attention
  k_gemm_qk<<<dim3(10, 1, 128), 256, 0, stream>>>(QBF, KBF, SC);
  k_softmax<<<dim3(16384), 256, 0, stream>>>(SC);
  k_gemm_pv<<<dim3(1, 4, 128), 256, 0, stream>>>(SC, VTB, ATTN);
  // 5. attn -> int8, output projection (i8, 128x256 3-buf; 256 blocks = 1 round)
  k_quant_attn<<<dim3(2048), 256, 0, stream>>>(ATTN, A8, AS);
  k_gemm_out8<<<dim3(16, 16), 512, 0, stream>>>(A8, W8 + 50331648ull, AS, wo_s, out);
  (void)in_sizes; (void)n_in; (void)out_size; (void)ws_size;
}

// Round 11
// 856.953 us; speedup vs baseline: 1.0563x; 1.0112x over previous
//
#include <hip/hip_runtime.h>
#include <cstdint>
#include <cstddef>

typedef __bf16 bf16;
typedef __attribute__((ext_vector_type(8))) __bf16 bf16x8;
typedef __attribute__((ext_vector_type(2))) __bf16 bf16x2;
typedef __attribute__((ext_vector_type(4))) float f32x4;
typedef __attribute__((ext_vector_type(2))) float f32x2;
typedef __attribute__((ext_vector_type(4))) int i32x4;

#define DIMN 4096
#define SEQ 512
#define MAXSEQ 2048
#define NHEAD 32
#define HD 128

#define BM 128
#define BN 128
#define BK 32    // bf16 core: 32 elems = 64 B rows

// ---------------- async global->LDS (wave-uniform base + lane*16) ----------
__device__ __forceinline__ void gld_lds16(const void* g, void* l) {
  __builtin_amdgcn_global_load_lds(
      (const __attribute__((address_space(1))) unsigned int*)g,
      (__attribute__((address_space(3))) unsigned int*)l, 16, 0, 0);
}

// ---------------- bf16 bt-GEMM core (m97 lineage, proven) ------------------
__device__ __forceinline__ void gemm_core(const bf16* Ablk, const bf16* Bblk,
                                          int lda, int ldb, int kmax,
                                          f32x4 acc[4][4], bf16* As, bf16* Bs) {
  const int tid = threadIdx.x;
  const int wave = tid >> 6;
  const int lane = tid & 63;
  const int wm = (wave >> 1) * 64;
  const int wn = (wave & 1) * 64;
  const int lrow = lane & 15;
  const int lkq8 = (lane >> 4) * 8;
  const int srow = wave * 32 + (lane >> 2);
  const int scol = (lane & 3) * 8;
  const bf16* Ag = Ablk + (size_t)srow * lda + scol;
  const bf16* Bg = Bblk + (size_t)srow * ldb + scol;
  bf16* lA = As + wave * 32 * BK;
  bf16* lB = Bs + wave * 32 * BK;

  for (int k0 = 0; k0 < kmax; k0 += BK) {
    __syncthreads();
    gld_lds16(Ag + k0, lA);
    gld_lds16(Ag + k0 + (size_t)16 * lda, lA + 16 * BK);
    gld_lds16(Bg + k0, lB);
    gld_lds16(Bg + k0 + (size_t)16 * ldb, lB + 16 * BK);
    __syncthreads();
    bf16x8 a[4], b[4];
#pragma unroll
    for (int i = 0; i < 4; ++i)
      a[i] = *(const bf16x8*)(As + (wm + i * 16 + lrow) * BK + lkq8);
#pragma unroll
    for (int i = 0; i < 4; ++i)
      b[i] = *(const bf16x8*)(Bs + (wn + i * 16 + lrow) * BK + lkq8);
#pragma unroll
    for (int mi = 0; mi < 4; ++mi)
#pragma unroll
      for (int ni = 0; ni < 4; ++ni)
        acc[mi][ni] = __builtin_amdgcn_mfma_f32_16x16x32_bf16(a[mi], b[ni], acc[mi][ni], 0, 0, 0);
  }
}

// ===========================================================================
// int8 128x256 tile, 3-buffer prefetch-2, full-8 XOR swizzle (round-10)
//
// Round-8 (866.5 us, PASS) had 4 full barriers per K-tile at 1 blk/CU --
// pure lockstep overhead, since BOTH phases only READ buf CUR and only
// WRITE buf STG: no intra-tile hazard exists. This version keeps buffers,
// lifetimes, swizzle, prologue and vmcnt depth IDENTICAL to round-8 but
// collapses the sync to ONE vmcnt(6)+barrier per K-tile (the true
// requirements: own-wave t+1 loads landed; cross-wave visibility; buf X
// last-read precedes next tile's stage-issue into X). ds_read->MFMA
// ordering is a plain data dep (compiler emits lgkmcnt).
// Per K-tile t (C = buf t%3, S = buf (t+2)%3; 6 chunk-loads/tile):
//   ds_read h0 | stage 3 chunks(t+2)->S | 16 MFMA
//   ds_read h1 | stage 3 chunks(t+2)->S | 16 MFMA
//   vmcnt(6); barrier
// Race-free: stage into S (holds t-1) is issued in tile t, i.e. after the
// boundary barrier of t-1 which followed t-1's last reads. vmcnt(6) at
// tile end retires exactly t+1's 6 loads (FIFO), leaving t+2's 6 in
// flight; the barrier then makes all waves' t+1 data visible. Tail stages
// (t+2>=32) read a few KB past the operand into adjacent mapped ws and
// land in dead LDS buffers -> harmless.
// ===========================================================================

#define PBAR do {                              \
    asm volatile("" ::: "memory");             \
    __builtin_amdgcn_sched_barrier(0);         \
    __builtin_amdgcn_s_barrier();              \
    __builtin_amdgcn_sched_barrier(0);         \
    asm volatile("" ::: "memory");             \
  } while (0)

// chunk = 64 rows x 128 B = 8 KB = one block-wide gld_lds (512 x 16 B)
#define STG_A(KT, C, LB) \
  gld_lds16(Asrc + (KT) * 128 + (size_t)(C) * 64 * DIMN, (LB) + (C) * 8192 + sdst)
#define STG_B(KT, C, LB) \
  gld_lds16(Bsrc + (KT) * 128 + (size_t)(C) * 64 * DIMN, (LB) + 16384 + (C) * 8192 + sdst)

#define LDA8(DST, MI, H, LB) \
  DST = *(const i32x4*)((LB) + (MI) * 2048 + aoff + ((H) ? g1off : g0off))
#define LDB8(DST, NI, H, LB) \
  DST = *(const i32x4*)((LB) + 16384 + (NI) * 2048 + boff + ((H) ? g1off : g0off))

#define MFMA16I()                                                           \
    __builtin_amdgcn_s_setprio(1);                                          \
    _Pragma("unroll") for (int _i = 0; _i < 4; ++_i)                        \
      _Pragma("unroll") for (int _n = 0; _n < 4; ++_n)                      \
        acc[_i][_n] = __builtin_amdgcn_mfma_i32_16x16x64_i8(                \
            a[_i], b[_n], acc[_i][_n], 0, 0, 0);                            \
    __builtin_amdgcn_s_setprio(0)

#define TILE3(T, CUR, STG) do {                                             \
    i32x4 a[4], b[4];                                                       \
    /* ---- h0: reads + first stage half + MFMA ---- */                     \
    _Pragma("unroll") for (int n = 0; n < 4; ++n) LDB8(b[n], n, 0, CUR);    \
    _Pragma("unroll") for (int i = 0; i < 4; ++i) LDA8(a[i], i, 0, CUR);    \
    STG_B((T) + 2, 0, STG);                                                 \
    STG_B((T) + 2, 1, STG);                                                 \
    STG_A((T) + 2, 0, STG);                                                 \
    MFMA16I();                                                              \
    /* ---- h1: reads + second stage half + MFMA ---- */                    \
    _Pragma("unroll") for (int n = 0; n < 4; ++n) LDB8(b[n], n, 1, CUR);    \
    _Pragma("unroll") for (int i = 0; i < 4; ++i) LDA8(a[i], i, 1, CUR);    \
    STG_B((T) + 2, 2, STG);                                                 \
    STG_B((T) + 2, 3, STG);                                                 \
    STG_A((T) + 2, 1, STG);                                                 \
    MFMA16I();                                                              \
    /* ---- single tile-boundary sync ---- */                               \
    asm volatile("s_waitcnt vmcnt(6)" ::: "memory");                        \
    __builtin_amdgcn_sched_barrier(0);                                      \
    __builtin_amdgcn_s_barrier();                                           \
    __builtin_amdgcn_sched_barrier(0);                                      \
  } while (0)

__device__ __forceinline__ void gemm128x256_i8(const char* __restrict__ Ablk,
                                               const char* __restrict__ Bblk,
                                               char* lds, i32x4 acc[4][4]) {
  const int tid = threadIdx.x;
  const int wave = tid >> 6, lane = tid & 63;
  const int wm = (wave >> 2) * 64, wn = (wave & 3) * 64;
  const int lrow = lane & 15, q = lane >> 4;
  // frag-read granule = ((h*4+q) ^ (lrow&7)) = ((h^hbit)<<2) | (q^(lrow&3))
  const int qx = q ^ (lrow & 3);
  const int hbit = (lrow >> 2) & 1;
  const int g0off = (((hbit) << 2) | qx) << 4;
  const int g1off = (((hbit ^ 1) << 2) | qx) << 4;
  const int aoff = (wm + lrow) * 128;
  const int boff = (wn + lrow) * 128;
  // staging: lane covers LDS (row = wave*8 + lane/8, granule = lane&7);
  // global granule = (lane&7) ^ (lane>>3) = g ^ (row&7)
  const int gsw = ((lane & 7) ^ (lane >> 3)) << 4;
  const char* Asrc = Ablk + (size_t)(wave * 8 + (lane >> 3)) * DIMN + gsw;
  const char* Bsrc = Bblk + (size_t)(wave * 8 + (lane >> 3)) * DIMN + gsw;
  const int sdst = wave * 1024;  // wave-uniform LDS dest base (+lane*16 by HW)
  char* const L0 = lds;
  char* const L1 = lds + 49152;
  char* const L2 = lds + 98304;

  // prologue: t0 -> L0 (6 loads), t1 -> L1 (6 loads)
  STG_A(0, 0, L0); STG_A(0, 1, L0);
  STG_B(0, 0, L0); STG_B(0, 1, L0); STG_B(0, 2, L0); STG_B(0, 3, L0);
  STG_A(1, 0, L1); STG_A(1, 1, L1);
  STG_B(1, 0, L1); STG_B(1, 1, L1); STG_B(1, 2, L1); STG_B(1, 3, L1);
  asm volatile("s_waitcnt vmcnt(6)" ::: "memory");  // t0 (6 oldest) landed
  __builtin_amdgcn_sched_barrier(0);
  __builtin_amdgcn_s_barrier();
  __builtin_amdgcn_sched_barrier(0);

  for (int t = 0; t < 30; t += 3) {
    TILE3(t, L0, L2);
    TILE3(t + 1, L1, L0);
    TILE3(t + 2, L2, L1);
  }
  TILE3(30, L0, L2);   // stages t=32 (garbage, dead buffer) -- harmless
  TILE3(31, L1, L0);   // stages t=33 (garbage, dead buffer) -- harmless
}

#define ACC_INIT_F(acc)                                 \
  f32x4 acc[4][4];                                      \
  _Pragma("unroll") for (int _i = 0; _i < 4; ++_i)      \
      _Pragma("unroll") for (int _j = 0; _j < 4; ++_j)  \
          acc[_i][_j] = f32x4{0.f, 0.f, 0.f, 0.f};

#define ACC_INIT_I8(acc)                                \
  i32x4 acc[4][4];                                      \
  _Pragma("unroll") for (int _i = 0; _i < 4; ++_i)      \
      _Pragma("unroll") for (int _j = 0; _j < 4; ++_j)  \
          acc[_i][_j] = i32x4{0, 0, 0, 0};

#define EPI_COORDS                                      \
  const int lane = threadIdx.x & 63;                    \
  const int wave = threadIdx.x >> 6;                    \
  const int wm = (wave >> 1) * 64, wn = (wave & 1) * 64;\
  const int cq = (lane >> 4) * 4, cc = lane & 15;

#define EPI8_COORDS                                      \
  const int lane = threadIdx.x & 63;                     \
  const int wave = threadIdx.x >> 6;                     \
  const int wm = (wave >> 2) * 64, wn = (wave & 3) * 64; \
  const int cq = (lane >> 4) * 4, cc = lane & 15;

// ---------------- prep über-kernel: pack weights + quant x + zero caches ---
// blocks [0,16384): pack 4 weights int32->int8 (exact)
// blocks [16384,18432): x fp32 -> int8 + per-row scale
// blocks [18432,67584): zero cache rows >= 512 (8 regions x 24 MB)
__global__ __launch_bounds__(256) void k_prep(
    const int* __restrict__ q0, const int* __restrict__ q1,
    const int* __restrict__ q2, const int* __restrict__ q3,
    char* __restrict__ w8, const float* __restrict__ x,
    char* __restrict__ x8, float* __restrict__ xs,
    float* __restrict__ ck, float* __restrict__ cv) {
  __shared__ float red[4];
  const int bx = blockIdx.x;
  const int tid = threadIdx.x;
  if (bx < 16384) {
    const int w = bx >> 12;
    const int* q = (w == 0) ? q0 : (w == 1) ? q1 : (w == 2) ? q2 : q3;
    char* wp = w8 + (size_t)w * 16777216ull;
    size_t i = ((size_t)(bx & 4095) * 256 + tid) * 16;
    const i32x4* qp = (const i32x4*)(q + i);
    i32x4 a = qp[0], b = qp[1], c = qp[2], d = qp[3];
    i32x4 o;
    o[0] = (a[0] & 255) | ((a[1] & 255) << 8) | ((a[2] & 255) << 16) | (a[3] << 24);
    o[1] = (b[0] & 255) | ((b[1] & 255) << 8) | ((b[2] & 255) << 16) | (b[3] << 24);
    o[2] = (c[0] & 255) | ((c[1] & 255) << 8) | ((c[2] & 255) << 16) | (c[3] << 24);
    o[3] = (d[0] & 255) | ((d[1] & 255) << 8) | ((d[2] & 255) << 16) | (d[3] << 24);
    *(i32x4*)(wp + i) = o;
  } else if (bx < 18432) {
    const int row = bx - 16384;
    const float* src = x + (size_t)row * DIMN + tid * 16;
    f32x4 v[4];
#pragma unroll
    for (int j = 0; j < 4; ++j) v[j] = ((const f32x4*)src)[j];
    float am = 0.f;
#pragma unroll
    for (int j = 0; j < 4; ++j)
#pragma unroll
      for (int e = 0; e < 4; ++e) am = fmaxf(am, fabsf(v[j][e]));
#pragma unroll
    for (int off = 32; off; off >>= 1) am = fmaxf(am, __shfl_xor(am, off, 64));
    if ((tid & 63) == 0) red[tid >> 6] = am;
    __syncthreads();
    am = fmaxf(fmaxf(red[0], red[1]), fmaxf(red[2], red[3]));
    const float inv = am > 0.f ? 127.f / am : 0.f;
    i32x4 o;
#pragma unroll
    for (int j = 0; j < 4; ++j) {
      int b0 = (int)rintf(v[j][0] * inv), b1 = (int)rintf(v[j][1] * inv);
      int b2 = (int)rintf(v[j][2] * inv), b3 = (int)rintf(v[j][3] * inv);
      o[j] = (b0 & 255) | ((b1 & 255) << 8) | ((b2 & 255) << 16) | (b3 << 24);
    }
    *(i32x4*)(x8 + (size_t)row * DIMN + tid * 16) = o;
    if (tid == 0) xs[row] = am * (1.f / 127.f);
  } else {
    const int z = bx - 18432;
    const int region = z / 6144;  // 0..7: (b, ck/cv)
    const int zoff = z - region * 6144;
    const int b = region >> 1;
    float* base = (region & 1) ? cv : ck;
    char* p = (char*)(base + ((size_t)b * MAXSEQ + SEQ) * DIMN);
    *(f32x4*)(p + (size_t)zoff * 4096 + tid * 16) = f32x4{0.f, 0.f, 0.f, 0.f};
  }
}

// ---------------- attn bf16 -> int8, per-row absmax scale ------------------
__global__ __launch_bounds__(256) void k_quant_attn(const bf16* __restrict__ at,
                                                    char* __restrict__ a8,
                                                    float* __restrict__ as_) {
  __shared__ float red[4];
  const int row = blockIdx.x, tid = threadIdx.x;
  const bf16* src = at + (size_t)row * DIMN + tid * 16;
  bf16x8 h0 = ((const bf16x8*)src)[0], h1 = ((const bf16x8*)src)[1];
  float f[16];
#pragma unroll
  for (int j = 0; j < 8; ++j) { f[j] = (float)h0[j]; f[8 + j] = (float)h1[j]; }
  float am = 0.f;
#pragma unroll
  for (int j = 0; j < 16; ++j) am = fmaxf(am, fabsf(f[j]));
#pragma unroll
  for (int off = 32; off; off >>= 1) am = fmaxf(am, __shfl_xor(am, off, 64));
  if ((tid & 63) == 0) red[tid >> 6] = am;
  __syncthreads();
  am = fmaxf(fmaxf(red[0], red[1]), fmaxf(red[2], red[3]));
  const float inv = am > 0.f ? 127.f / am : 0.f;
  i32x4 o;
#pragma unroll
  for (int j = 0; j < 4; ++j) {
    int b0 = (int)rintf(f[j * 4 + 0] * inv), b1 = (int)rintf(f[j * 4 + 1] * inv);
    int b2 = (int)rintf(f[j * 4 + 2] * inv), b3 = (int)rintf(f[j * 4 + 3] * inv);
    o[j] = (b0 & 255) | ((b1 & 255) << 8) | ((b2 & 255) << 16) | (b3 << 24);
  }
  *(i32x4*)(a8 + (size_t)row * DIMN + tid * 16) = o;
  if (tid == 0) as_[row] = am * (1.f / 127.f);
}

// ---------------- QKV projection (i8, 128x256 3-buf) -----------------------
__global__ __launch_bounds__(512, 2) void k_gemm_qkv8(
    const char* __restrict__ X8, const char* __restrict__ W8,
    const float* __restrict__ xs, const float* __restrict__ sq,
    const float* __restrict__ sk, const float* __restrict__ sv,
    const float* __restrict__ fc, const float* __restrict__ fs,
    const int* __restrict__ idx, bf16* __restrict__ qbf,
    bf16* __restrict__ kbf, float* __restrict__ ck, float* __restrict__ cv) {
  __shared__ __align__(16) char lds[147456];
  const int n0 = blockIdx.x * 256;
  const int m0 = blockIdx.y * 128;
  const int z = blockIdx.z;
  const char* W = W8 + (size_t)z * 16777216ull;
  const float* sw = (z == 0) ? sq : (z == 1) ? sk : sv;
  ACC_INIT_I8(acc);
  gemm128x256_i8(X8 + (size_t)m0 * DIMN, W + (size_t)n0 * DIMN, lds, acc);
  EPI8_COORDS;
  if (z < 2) {
    bf16* dst = (z == 0) ? qbf : kbf;
#pragma unroll
    for (int mi = 0; mi < 4; ++mi)
#pragma unroll
      for (int ni = 0; ni < 4; ++ni)
#pragma unroll
        for (int r = 0; r < 4; ++r) {
          const int row = m0 + wm + mi * 16 + cq + r;
          const int col = n0 + wn + ni * 16 + cc;
          const float v = (float)acc[mi][ni][r] * xs[row] * sw[col];
          const float pv = __shfl_xor(v, 1, 64);  // partner col^1, same row
          const int s = row & 511, b = row >> 9;
          const int hd = col & 127, h = col >> 7;
          const int d2 = hd >> 1;
          const float c = fc[s * 64 + d2], sn = fs[s * 64 + d2];
          const float o = (col & 1) ? (pv * sn + v * c) : (v * c - pv * sn);
          dst[(((size_t)(b * NHEAD + h)) * SEQ + s) * HD + hd] = (bf16)o;
          if (z == 1) {
            const int pos = idx[s];
            ck[((size_t)b * MAXSEQ + pos) * DIMN + col] = o;
          }
        }
  } else {
#pragma unroll
    for (int mi = 0; mi < 4; ++mi)
#pragma unroll
      for (int ni = 0; ni < 4; ++ni)
#pragma unroll
        for (int r = 0; r < 4; ++r) {
          const int row = m0 + wm + mi * 16 + cq + r;
          const int col = n0 + wn + ni * 16 + cc;
          const int s = row & 511, b = row >> 9;
          cv[((size_t)b * MAXSEQ + s) * DIMN + col] =
              (float)acc[mi][ni][r] * xs[row] * sw[col];
        }
  }
}

// ---------------- V transpose: cache_v (b,s<512,h,d) fp32 -> (b,h,d,s) bf16
__global__ __launch_bounds__(256) void k_vt(const float* __restrict__ cv,
                                            bf16* __restrict__ vt) {
  __shared__ float tile[32][129];
  const int s0 = blockIdx.x * 32;
  const int bh = blockIdx.y;
  const int b = bh >> 5, h = bh & 31;
  const int tid = threadIdx.x;
  const float* src = cv + (size_t)b * MAXSEQ * DIMN + h * HD;
#pragma unroll
  for (int p = 0; p < 16; ++p) {
    const int row = p * 2 + (tid >> 7);
    const int d = tid & 127;
    tile[row][d] = src[(size_t)(s0 + row) * DIMN + d];
  }
  __syncthreads();
  bf16* dst = vt + (size_t)bh * HD * SEQ;
#pragma unroll
  for (int c = 0; c < 16; ++c) {
    const int d = c * 8 + (tid >> 5);
    const int sl = tid & 31;
    dst[(size_t)d * SEQ + s0 + sl] = (bf16)tile[sl][d];
  }
}

// ---------------- QK^T: packed causal grid, scores bf16 --------------------
__constant__ int g_tm[10] = {0, 1, 1, 2, 2, 2, 3, 3, 3, 3};
__constant__ int g_tn[10] = {0, 0, 1, 0, 1, 2, 0, 1, 2, 3};

__global__ __launch_bounds__(256, 2) void k_gemm_qk(
    const bf16* __restrict__ qb, const bf16* __restrict__ kb,
    bf16* __restrict__ sc) {
  const int m0 = g_tm[blockIdx.x] * BM;
  const int n0 = g_tn[blockIdx.x] * BN;
  const int bh = blockIdx.z;
  __shared__ __align__(16) bf16 As[BM * BK];
  __shared__ __align__(16) bf16 Bs[BN * BK];
  ACC_INIT_F(acc);
  gemm_core(qb + (size_t)bh * SEQ * HD + (size_t)m0 * HD,
            kb + (size_t)bh * SEQ * HD + (size_t)n0 * HD, HD, HD, HD, acc, As, Bs);
  EPI_COORDS;
  bf16* dst = sc + (size_t)bh * SEQ * SEQ;
#pragma unroll
  for (int mi = 0; mi < 4; ++mi)
#pragma unroll
    for (int ni = 0; ni < 4; ++ni)
#pragma unroll
      for (int r = 0; r < 4; ++r) {
        const int row = m0 + wm + mi * 16 + cq + r;
        const int col = n0 + wn + ni * 16 + cc;
        dst[(size_t)row * SEQ + col] = (bf16)(acc[mi][ni][r] * 0.08838834764831845f);
      }
}

// ---------------- row softmax, in-place ------------------------------------
__global__ __launch_bounds__(256) void k_softmax(bf16* __restrict__ sc) {
  const int row = blockIdx.x * 4 + (threadIdx.x >> 6);
  const int lane = threadIdx.x & 63;
  const int q = row & 511;
  bf16* p = sc + (size_t)row * SEQ + lane * 8;
  bf16x8 v8 = *(const bf16x8*)p;
  float lv[8];
  float m = -3.0e38f;
#pragma unroll
  for (int j = 0; j < 8; ++j) {
    const int kj = lane * 8 + j;
    lv[j] = (kj <= q) ? (float)v8[j] : -3.0e38f;
    m = fmaxf(m, lv[j]);
  }
#pragma unroll
  for (int off = 32; off; off >>= 1) m = fmaxf(m, __shfl_xor(m, off, 64));
  float e[8];
  float sum = 0.f;
#pragma unroll
  for (int j = 0; j < 8; ++j) {
    e[j] = (lane * 8 + j <= q) ? __expf(lv[j] - m) : 0.f;
    sum += e[j];
  }
#pragma unroll
  for (int off = 32; off; off >>= 1) sum += __shfl_xor(sum, off, 64);
  const float r = 1.f / sum;
  bf16x8 o;
#pragma unroll
  for (int j = 0; j < 8; ++j) o[j] = (bf16)(e[j] * r);
  *(bf16x8*)p = o;
}

// ---------------- P @ V, causal K-bound ------------------------------------
__global__ __launch_bounds__(256, 2) void k_gemm_pv(
    const bf16* __restrict__ P, const bf16* __restrict__ vt,
    bf16* __restrict__ attn) {
  const int m0 = blockIdx.y * BM;
  const int bh = blockIdx.z;
  const int kmax = m0 + BM;
  __shared__ __align__(16) bf16 As[BM * BK];
  __shared__ __align__(16) bf16 Bs[BN * BK];
  ACC_INIT_F(acc);
  gemm_core(P + (size_t)bh * SEQ * SEQ + (size_t)m0 * SEQ,
            vt + (size_t)bh * HD * SEQ, SEQ, SEQ, kmax, acc, As, Bs);
  EPI_COORDS;
  const int b = bh >> 5, h = bh & 31;
#pragma unroll
  for (int mi = 0; mi < 4; ++mi)
#pragma unroll
    for (int ni = 0; ni < 4; ++ni)
#pragma unroll
      for (int r = 0; r < 4; ++r) {
        const int row = m0 + wm + mi * 16 + cq + r;
        const int col = wn + ni * 16 + cc;  // < 128
        attn[((size_t)(b * SEQ + row)) * DIMN + h * HD + col] = (bf16)acc[mi][ni][r];
      }
}

// ---------------- output projection (i8, 128x256 3-buf) --------------------
__global__ __launch_bounds__(512, 2) void k_gemm_out8(
    const char* __restrict__ A8, const char* __restrict__ WO8,
    const float* __restrict__ as_, const float* __restrict__ so,
    float* __restrict__ out) {
  __shared__ __align__(16) char lds[147456];
  const int n0 = blockIdx.x * 256;
  const int m0 = blockIdx.y * 128;
  ACC_INIT_I8(acc);
  gemm128x256_i8(A8 + (size_t)m0 * DIMN, WO8 + (size_t)n0 * DIMN, lds, acc);
  EPI8_COORDS;
#pragma unroll
  for (int mi = 0; mi < 4; ++mi)
#pragma unroll
    for (int ni = 0; ni < 4; ++ni)
#pragma unroll
      for (int r = 0; r < 4; ++r) {
        const int row = m0 + wm + mi * 16 + cq + r;
        const int col = n0 + wn + ni * 16 + cc;
        out[(size_t)row * DIMN + col] = (float)acc[mi][ni][r] * as_[row] * so[col];
      }
}

// ===========================================================================
extern "C" void kernel_launch(void* const* d_in, const int* in_sizes, int n_in,
                              void* d_out, int out_size, void* d_ws, size_t ws_size,
                              hipStream_t stream) {
  const float* x = (const float*)d_in[0];
  const float* fc = (const float*)d_in[1];
  const float* fs = (const float*)d_in[2];
  const int* idx = (const int*)d_in[4];
  const int* wq_q = (const int*)d_in[7];
  const int* wk_q = (const int*)d_in[9];
  const int* wv_q = (const int*)d_in[11];
  const int* wo_q = (const int*)d_in[13];
  const float* wq_s = (const float*)d_in[8];
  const float* wk_s = (const float*)d_in[10];
  const float* wv_s = (const float*)d_in[12];
  const float* wo_s = (const float*)d_in[14];

  float* out = (float*)d_out;                 // (4,512,4096) fp32
  float* ck_out = out + 8388608;              // (4,2048,32,128) fp32
  float* cv_out = ck_out + 33554432;          // (4,2048,32,128) fp32

  // workspace layout (~230 MiB; harness ws is ~1.15 GiB per poison fills)
  char* ws = (char*)d_ws;
  char* W8   = ws;                            // 64 MiB: WQ8,WK8,WV8,WO8
  char* X8   = ws + 67108864ull;              // 8.4 MiB
  float* XS  = (float*)(ws + 75497472ull);    // 2048 f
  float* AS  = (float*)(ws + 75513856ull);    // 2048 f
  bf16* QBF  = (bf16*)(ws + 83886080ull);     // (b,h,s,d) 16.8 MiB
  bf16* KBF  = (bf16*)(ws + 100663296ull);
  bf16* VTB  = (bf16*)(ws + 117440512ull);    // (b,h,d,s)
  bf16* ATTN = (bf16*)(ws + 134217728ull);
  char* A8   = ws + 150994944ull;             // 8.4 MiB
  bf16* SC   = (bf16*)(ws + 167772160ull);    // 64 MiB scores

  // 1. prep: pack weights (exact), quant x, zero cache rows >= 512
  k_prep<<<dim3(67584), 256, 0, stream>>>(wq_q, wk_q, wv_q, wo_q, W8, x, X8, XS,
                                          ck_out, cv_out);
  // 2. QKV projections (i8, 128x256 3-buf, 1-barrier/tile), fused rotary epi
  //    768 blocks = 3 exact rounds of 256 CUs at 1 block/CU
  k_gemm_qkv8<<<dim3(16, 16, 3), 512, 0, stream>>>(
      X8, W8, XS, wq_s, wk_s, wv_s, fc, fs, idx, QBF, KBF, ck_out, cv_out);
  // 3. V^T bf16 (b,h,d,s)
  k_vt<<<dim3(16, 128), 256, 0, stream>>>(cv_out, VTB);
  // 4. attention
  k_gemm_qk<<<dim3(10, 1, 128), 256, 0, stream>>>(QBF, KBF, SC);
  k_softmax<<<dim3(16384), 256, 0, stream>>>(SC);
  k_gemm_pv<<<dim3(1, 4, 128), 256, 0, stream>>>(SC, VTB, ATTN);
  // 5. attn -> int8, output projection (i8, 128x256 3-buf; 256 blocks = 1 round)
  k_quant_attn<<<dim3(2048), 256, 0, stream>>>(ATTN, A8, AS);
  k_gemm_out8<<<dim3(16, 16), 512, 0, stream>>>(A8, W8 + 50331648ull, AS, wo_s, out);
  (void)in_sizes; (void)n_in; (void)out_size; (void)ws_size;
}